// Round 3
// baseline (124.335 us; speedup 1.0000x reference)
//
#include <hip/hip_runtime.h>

constexpr int B    = 4;
constexpr int CIN  = 192;
constexpr int COUT = 192;
constexpr int NN   = 16384;
constexpr int KK   = 16;
constexpr int NG   = 4;    // groups
constexpr int GIN  = 48;   // fan_in per group
constexpr int GOUT = 48;   // out channels per group
constexpr int NT   = 64;   // nodes per block (R0 geometry: 1024 blocks = 4/CU)
constexpr int TPB  = 192;
constexpr int OST  = NT + 4;  // o_lds stride (68 floats = 272 B, 16B-aligned rows)

// ---------------------------------------------------------------------------
// Kernel 1: x (B, C, N) -> xt (B, G, N, 48): each (b,g) slice is a contiguous
// 3.15 MB region (fits one XCD's 4 MB L2); each node's group-slice is 192 B
// contiguous and 16B-aligned.  (unchanged — runs at ~L3 roofline)
// ---------------------------------------------------------------------------
__global__ __launch_bounds__(256) void transpose_x(const float* __restrict__ x,
                                                   float* __restrict__ xt) {
    __shared__ float tile[32][33];
    const int b  = blockIdx.z;
    const int n0 = blockIdx.x * 32;
    const int c0 = blockIdx.y * 32;
    const int tx = threadIdx.x;  // 0..31
    const int ty = threadIdx.y;  // 0..7
    const float* xb  = x  + (size_t)b * CIN * NN;
    float*       xtb = xt + (size_t)b * NN * CIN;   // = b * (NG*NN*GIN)
#pragma unroll
    for (int i = 0; i < 32; i += 8)
        tile[ty + i][tx] = xb[(size_t)(c0 + ty + i) * NN + (n0 + tx)];
    __syncthreads();
#pragma unroll
    for (int i = 0; i < 32; i += 8) {
        const int c = c0 + tx, n = n0 + ty + i;
        xtb[((size_t)(c / GIN) * NN + n) * GIN + (c % GIN)] = tile[tx][ty + i];
    }
}

// ---------------------------------------------------------------------------
// Kernel 2: R0 geometry (NT=64, TPB=192, 1024 blocks = 4/CU, 12 waves/CU),
// which gave compulsory-only FETCH (51.6 MB).  THE change this round:
// per-wave memory-level parallelism in the gather.  R0-R2 all had VGPR<=64
// with wv[12] pinning 48 of them -> only ~2-3 gather loads in flight ->
// gather ran at L2 *latency*, not L2 bandwidth.  Now:
//   - __launch_bounds__(192,3): VGPR cap 170, still 3 waves/SIMD min.
//   - gather issues all 17 float4 loads into statically-indexed regs (vv[16])
//     BEFORE any adds, then tree-sums.  ~17 loads in flight per wave.
// ---------------------------------------------------------------------------
__global__ __launch_bounds__(TPB, 3) void gin_main(const float* __restrict__ xt,
                                                   const int*   __restrict__ idx,
                                                   const float* __restrict__ w,
                                                   const float* __restrict__ bias,
                                                   const float* __restrict__ eps,
                                                   float* __restrict__ out) {
    __shared__ __align__(16) float h_lds[NT * GIN];   // [64][48] = 12 KB
    __shared__ __align__(16) float o_lds[GOUT * OST]; // [48][68] = 12.75 KB
    __shared__ int   idx_lds[NT * KK];                // 4 KB

    const int tid = threadIdx.x;
    const int blk = blockIdx.x;
    const int b   = blk & 3;
    const int n0  = (blk >> 2) * NT;

    const float e1 = 1.0f + eps[0];

    // stage this tile's neighbor indices once (shared by all 4 groups)
    {
        const int* gi = idx + ((size_t)b * NN + n0) * KK;
        for (int i = tid; i < NT * KK; i += TPB) idx_lds[i] = gi[i];
    }

    // gather mapping: 12 lanes x float4 cover one 192 B node-slice
    const int e    = tid % 12;   // float4 index within slice
    const int isub = tid / 12;   // 0..15 (node sub-index)
    // gemm mapping
    const int co   = tid % GOUT; // 0..47
    const int q    = tid / GOUT; // 0..3 (node quarter, 16 rows each)

    const float* xb = xt  + (size_t)b * NN * CIN;      // batch base
    float*       ob = out + (size_t)b * COUT * NN;

    __syncthreads();

    for (int g = 0; g < NG; ++g) {
        // prefetch this group's weight row + bias (stay in flight during gather)
        float4 wv[12];
        {
            const float* wr = w + (size_t)(g * GOUT + co) * GIN;
#pragma unroll
            for (int ii = 0; ii < 12; ++ii) wv[ii] = ((const float4*)wr)[ii];
        }
        const float bi = bias[g * GOUT + co];

        // ---- Phase 1: gather + sum, max-MLP form ----
        const float4* xg4 = (const float4*)(xb + (size_t)g * NN * GIN);
#pragma unroll
        for (int r = 0; r < 4; ++r) {
            const int i = isub + 16 * r;
            // all 16 neighbor indices first (LDS broadcast reads, cheap)
            const int4* ip = (const int4*)(idx_lds + i * KK);
            const int4 j0 = ip[0], j1 = ip[1], j2 = ip[2], j3 = ip[3];
            const int js[16] = {j0.x, j0.y, j0.z, j0.w, j1.x, j1.y, j1.z, j1.w,
                                j2.x, j2.y, j2.z, j2.w, j3.x, j3.y, j3.z, j3.w};
            // issue all 17 loads before any arithmetic (32-bit indices:
            // js*12+e < 196608 -> saddr-form global_load_dwordx4)
            const float4 sv = xg4[(n0 + i) * 12 + e];
            float4 vv[16];
#pragma unroll
            for (int k = 0; k < 16; ++k) vv[k] = xg4[js[k] * 12 + e];
            // tree-sum (short dependence chain)
#pragma unroll
            for (int st = 8; st >= 1; st >>= 1)
#pragma unroll
                for (int k = 0; k < st; ++k) {
                    vv[k].x += vv[k + st].x; vv[k].y += vv[k + st].y;
                    vv[k].z += vv[k + st].z; vv[k].w += vv[k + st].w;
                }
            float4 acc;
            acc.x = fmaf(e1, sv.x, vv[0].x);
            acc.y = fmaf(e1, sv.y, vv[0].y);
            acc.z = fmaf(e1, sv.z, vv[0].z);
            acc.w = fmaf(e1, sv.w, vv[0].w);
            ((float4*)(h_lds + i * GIN))[e] = acc;     // wave-linear, conflict-free
        }
        __syncthreads();

        // ---- Phase 2: grouped GEMM (weights in VGPRs, h broadcast from LDS) ----
        float a[16];
#pragma unroll
        for (int i2 = 0; i2 < 16; ++i2) {
            const int i = q * 16 + i2;
            const float* hr = h_lds + i * GIN;
            float s = bi;
#pragma unroll
            for (int ii = 0; ii < 12; ++ii) {
                const float4 hv = ((const float4*)hr)[ii];
                s = fmaf(wv[ii].x, hv.x, s);
                s = fmaf(wv[ii].y, hv.y, s);
                s = fmaf(wv[ii].z, hv.z, s);
                s = fmaf(wv[ii].w, hv.w, s);
            }
            a[i2] = fmaxf(s, 0.0f);
        }

        // ---- Phase 3: restage (float4) + coalesced global write ----
        {
            float4* orow = (float4*)(o_lds + co * OST + q * 16);  // 272B rows
            orow[0] = make_float4(a[0],  a[1],  a[2],  a[3]);
            orow[1] = make_float4(a[4],  a[5],  a[6],  a[7]);
            orow[2] = make_float4(a[8],  a[9],  a[10], a[11]);
            orow[3] = make_float4(a[12], a[13], a[14], a[15]);
        }
        __syncthreads();

        const int row = tid / 16;   // 0..11
        const int ee  = tid % 16;   // float4 index within 64-float row
#pragma unroll
        for (int p = 0; p < 4; ++p) {
            const int r2 = p * 12 + row;
            const float4 v = ((const float4*)(o_lds + r2 * OST))[ee];
            ((float4*)(ob + (size_t)(g * GOUT + r2) * NN + n0))[ee] = v;
        }
        __syncthreads();   // o_lds/h_lds safe to overwrite next group
    }
}

// ---------------------------------------------------------------------------
extern "C" void kernel_launch(void* const* d_in, const int* in_sizes, int n_in,
                              void* d_out, int out_size, void* d_ws, size_t ws_size,
                              hipStream_t stream) {
    const float* x      = (const float*)d_in[0];
    const int*   edge   = (const int*)  d_in[1];  // edge_index[0] = first half
    const float* weight = (const float*)d_in[2];
    const float* bias   = (const float*)d_in[3];
    const float* eps    = (const float*)d_in[4];
    float*       out    = (float*)d_out;
    float*       xt     = (float*)d_ws;           // B*N*192 floats = 50.3 MB

    dim3 tblk(32, 8);
    dim3 tgrd(NN / 32, CIN / 32, B);
    transpose_x<<<tgrd, tblk, 0, stream>>>(x, xt);

    gin_main<<<B * (NN / NT), TPB, 0, stream>>>(xt, edge, weight, bias, eps, out);
}